// Round 11
// baseline (245.816 us; speedup 1.0000x reference)
//
#include <hip/hip_runtime.h>
#include <math.h>

// Problem constants
#define NPOS   65536        // 16*64*64 positions
#define NE     1024         // codebook size
#define EDIM   64
#define HW     4096         // 64*64
#define BETA   0.25

// Output layout (floats) in d_out, reference return order:
// loss(1), z_q_st(16*64*64*64), perplexity(1), min_encodings(65536*1024), indices(65536)
#define OUT_LOSS 0LL
#define OUT_ZQ   1LL
#define OUT_PERP 4194305LL
#define OUT_ENC  4194306LL
#define OUT_IDX  71303170LL

#define POSB 128            // positions per block
#define JT   128            // code-tile width (8 tiles cover 1024)

// numpy pairwise_sum for n=64 (8 accumulators, stride 8, tree combine) of squares.
__device__ __forceinline__ float pairwise_sum_sq64(const float v[64]) {
#pragma clang fp contract(off)
    float r[8];
#pragma unroll
    for (int k = 0; k < 8; ++k) r[k] = v[k] * v[k];
#pragma unroll
    for (int i = 8; i < 64; i += 8) {
#pragma unroll
        for (int k = 0; k < 8; ++k) {
            float s = v[i + k] * v[i + k];
            r[k] = r[k] + s;
        }
    }
    return ((r[0] + r[1]) + (r[2] + r[3])) + ((r[4] + r[5]) + (r[6] + r[7]));
}

// K0: codebook norms + transposed codebook + zero counts + zero loss accumulator
__global__ void vq_prep(const float* __restrict__ emb, float* __restrict__ enorm,
                        float* __restrict__ embT, int* __restrict__ counts,
                        double* __restrict__ lacc) {
    int t = blockIdx.x * 256 + threadIdx.x;   // 0..1023
    if (t < NE) {
        float v[64];
#pragma unroll
        for (int c = 0; c < 64; ++c) v[c] = emb[t * 64 + c];
        enorm[t] = pairwise_sum_sq64(v);
#pragma unroll
        for (int c = 0; c < 64; ++c) embT[c * NE + t] = v[c];  // coalesced
        counts[t] = 0;
    }
    if (t == 0) *lacc = 0.0;
}

// K1: main. grid = 512 blocks x 128 threads (2 waves), 2 blocks/CU.
// Thread tile = 16 pos x 8 codes (128 acc). Per c per wave: 4 z-b128 + 2 e-b128
// = 72 LDS-cyc vs 256 FMA-cyc -> VALU-bound (R10 was 8x8 tile: LDS-bound 384).
// Pos ownership: {4T+i, 32+4T+i, 64+4T+i, 96+4T+i}, T=tid>>4 (b128 reads span
// banks 0..15 x4 addrs, conflict-free). Code ownership: {4tc+u} u {64+4tc+u},
// tc=tid&15 (2-way alias = free). One-hot fused back in (R10's separate
// kernel serialized 55 us after main).
// Bit-exactness: dot = single accumulator, sequential c FMA; dist/argmin
// order identical to verified R9/R10.
__global__ __launch_bounds__(128, 1)
void vq_main(const float* __restrict__ z, const float* __restrict__ emb,
             const float* __restrict__ embT, const float* __restrict__ enorm,
             int* __restrict__ counts, double* __restrict__ lacc,
             float* __restrict__ out) {
    __shared__ float z_lds[64 * POSB];      // [c][p]  32 KB
    __shared__ float e_lds[64 * JT];        // [c][q]  32 KB
    __shared__ float enorm_lds[NE];         // 4 KB
    __shared__ float szn_lds[POSB];
    __shared__ int   run_j_lds[POSB];

    const int tid = threadIdx.x;            // 0..127
    const int T   = tid >> 4;               // 0..7  pos-group
    const int tc  = tid & 15;               // 0..15 code-group
    const int n0  = blockIdx.x * POSB;
    const int b   = n0 >> 12;
    const int hw0 = n0 & 4095;
    const int zbase = b * (64 * HW) + hw0;

    // ---- stage z tile (64 c x 128 pos), float4 both sides: 16 f4/thread ----
#pragma unroll
    for (int it = 0; it < 16; ++it) {
        const int idx4 = it * 128 + tid;          // 0..2047 float4s
        const int c    = idx4 >> 5;               // 32 float4 per c-row
        const int p4   = idx4 & 31;
        const float4 v = *(const float4*)(z + zbase + c * HW + p4 * 4);
        *(float4*)(&z_lds[c * POSB + p4 * 4]) = v;
    }
    // ---- stage enorm ----
#pragma unroll
    for (int it = 0; it < 8; ++it) enorm_lds[it * 128 + tid] = enorm[it * 128 + tid];
    __syncthreads();

    // ---- szn per position (pos = tid), numpy pairwise order (bit-identical) ----
    {
#pragma clang fp contract(off)
        float r[8];
#pragma unroll
        for (int k = 0; k < 8; ++k) { float x = z_lds[k * POSB + tid]; r[k] = x * x; }
#pragma unroll
        for (int i = 8; i < 64; i += 8) {
#pragma unroll
            for (int k = 0; k < 8; ++k) {
                float x = z_lds[(i + k) * POSB + tid];
                float s = x * x;
                r[k] = r[k] + s;
            }
        }
        szn_lds[tid] = ((r[0] + r[1]) + (r[2] + r[3])) + ((r[4] + r[5]) + (r[6] + r[7]));
    }
    __syncthreads();

    // my 16 positions: pos = pc*32 + T*4 + i  (pc 0..3, i 0..3)
    float my_szn[16];
#pragma unroll
    for (int pc = 0; pc < 4; ++pc) {
        const float4 s4 = *(const float4*)(&szn_lds[pc * 32 + T * 4]);
        my_szn[pc * 4 + 0] = s4.x; my_szn[pc * 4 + 1] = s4.y;
        my_szn[pc * 4 + 2] = s4.z; my_szn[pc * 4 + 3] = s4.w;
    }
    float run_d[16];
    int   run_j[16];
#pragma unroll
    for (int p = 0; p < 16; ++p) { run_d[p] = 3.4e38f; run_j[p] = 0; }

    // ---- main loop over 8 code tiles ----
    for (int jo = 0; jo < 8; ++jo) {
        const int j0 = jo * JT;

        // stage e tile (64 c x 128 codes): 16 f4/thread
#pragma unroll
        for (int it = 0; it < 16; ++it) {
            const int idx4 = it * 128 + tid;
            const int c    = idx4 >> 5;
            const int q4   = idx4 & 31;
            const float4 v = *(const float4*)(embT + c * NE + j0 + q4 * 4);
            *(float4*)(&e_lds[c * JT + q4 * 4]) = v;
        }
        __syncthreads();

        float acc[16][8];
#pragma unroll
        for (int p = 0; p < 16; ++p)
#pragma unroll
            for (int u = 0; u < 8; ++u) acc[p][u] = 0.0f;

        // k-loop: sequential c, single accumulator per (pos,code) pair
#pragma unroll 2
        for (int c = 0; c < 64; ++c) {
            float zf[16];
#pragma unroll
            for (int pc = 0; pc < 4; ++pc) {
                const float4 v = *(const float4*)(&z_lds[c * POSB + pc * 32 + T * 4]);
                zf[pc * 4 + 0] = v.x; zf[pc * 4 + 1] = v.y;
                zf[pc * 4 + 2] = v.z; zf[pc * 4 + 3] = v.w;
            }
            const float4 ea = *(const float4*)(&e_lds[c * JT + tc * 4]);
            const float4 eb = *(const float4*)(&e_lds[c * JT + 64 + tc * 4]);
            const float ef[8] = {ea.x, ea.y, ea.z, ea.w, eb.x, eb.y, eb.z, eb.w};
#pragma unroll
            for (int p = 0; p < 16; ++p)
#pragma unroll
                for (int u = 0; u < 8; ++u)
                    acc[p][u] = fmaf(zf[p], ef[u], acc[p][u]);
        }

        // distances + tie-correct argmin
        const float4 enA = *(const float4*)(&enorm_lds[j0 + tc * 4]);
        const float4 enB = *(const float4*)(&enorm_lds[j0 + 64 + tc * 4]);
        const float enAf[4] = {enA.x, enA.y, enA.z, enA.w};
        const float enBf[4] = {enB.x, enB.y, enB.z, enB.w};
#pragma unroll
        for (int p = 0; p < 16; ++p) {
            const float sz = my_szn[p];
            float bd = 3.4e38f;
            int   bj = 0;
            // ascending j within this thread: {4tc..4tc+3} then {64+4tc..+3}
#pragma unroll
            for (int u = 0; u < 4; ++u) {
                const int j = j0 + tc * 4 + u;
                const float dj = (sz + enAf[u]) - 2.0f * acc[p][u];
                if (dj < bd) { bd = dj; bj = j; }
            }
#pragma unroll
            for (int u = 0; u < 4; ++u) {
                const int j = j0 + 64 + tc * 4 + u;
                const float dj = (sz + enBf[u]) - 2.0f * acc[p][4 + u];
                if (dj < bd) { bd = dj; bj = j; }
            }
            // lex-min reduce across the 16 tc-lanes (same T); ties -> lower j
#pragma unroll
            for (int m = 1; m < 16; m <<= 1) {
                const float od = __shfl_xor(bd, m, 64);
                const int   oj = __shfl_xor(bj, m, 64);
                if (od < bd || (od == bd && oj < bj)) { bd = od; bj = oj; }
            }
            // ascending tile order + strict < keeps earliest index on ties
            if (bd < run_d[p]) { run_d[p] = bd; run_j[p] = bj; }
        }
        __syncthreads();   // protect e_lds for next tile
    }

    // publish per-position argmin (all 16 tc-lanes hold identical results)
    if (tc == 0) {
#pragma unroll
        for (int pc = 0; pc < 4; ++pc)
#pragma unroll
            for (int i = 0; i < 4; ++i)
                run_j_lds[pc * 32 + T * 4 + i] = run_j[pc * 4 + i];
    }
    __syncthreads();

    // ---- idx + counts (pos = tid) ----
    const int myj = run_j_lds[tid];
    atomicAdd(&counts[myj], 1);
    out[OUT_IDX + n0 + tid] = (float)myj;   // indices as f32 values

    // ---- z_q_st = z + (z_q - z) + loss partials (pos = tid, all 64 c) ----
    {
        double acc2 = 0.0;
#pragma unroll 8
        for (int c = 0; c < 64; ++c) {
            const float zc = z_lds[c * POSB + tid];
            const float ec = emb[myj * 64 + c];
            const float t  = __fsub_rn(ec, zc);   // z_q - z
            const float o  = __fadd_rn(zc, t);    // z + (z_q - z)
            out[OUT_ZQ + (long long)b * (64LL * HW) + (long long)c * HW + hw0 + tid] = o;
            const float s = __fmul_rn(t, t);      // (z_q - z)^2 rounded f32
            acc2 += (double)s;
        }
#pragma unroll
        for (int off = 32; off > 0; off >>= 1) acc2 += __shfl_down(acc2, off);
        if ((tid & 63) == 0) atomicAdd(lacc, acc2);
    }

    // ---- one-hot: 128 rows x 512 float2, 4 float2/thread/row ----
    {
        float2* __restrict__ enc2 = (float2*)(out + OUT_ENC);
        for (int r = 0; r < POSB; ++r) {
            const int ir = run_j_lds[r];
            const long long rowb = (long long)(n0 + r) * 512;
#pragma unroll
            for (int q = 0; q < 4; ++q) {
                const int g  = q * 128 + tid;
                const int c0 = g * 2;
                float2 v;
                v.x = (c0     == ir) ? 1.0f : 0.0f;
                v.y = (c0 + 1 == ir) ? 1.0f : 0.0f;
                enc2[rowb + g] = v;
            }
        }
    }
}

// K2: perplexity + loss finalize. 1 block x 1024 threads.
__global__ void vq_finalize(const int* __restrict__ counts,
                            const double* __restrict__ lacc,
                            float* __restrict__ out) {
    __shared__ float red[1024];
    const int t = threadIdx.x;
    const float p = (float)counts[t] * (1.0f / 65536.0f); // exact (count int, /2^16)
    const float term = p * logf(p + 1e-10f);
    red[t] = term;
    __syncthreads();
    for (int s = 512; s > 0; s >>= 1) {
        if (t < s) red[t] += red[t + s];
        __syncthreads();
    }
    if (t == 0) {
        out[OUT_PERP] = expf(-red[0]);
        out[OUT_LOSS] = (float)(BETA * (*lacc / 4194304.0));
    }
}

extern "C" void kernel_launch(void* const* d_in, const int* in_sizes, int n_in,
                              void* d_out, int out_size, void* d_ws, size_t ws_size,
                              hipStream_t stream) {
    const float* z   = (const float*)d_in[0];   // (16,64,64,64) f32
    const float* emb = (const float*)d_in[1];   // (1024,64) f32
    float* out = (float*)d_out;

    double* lacc  = (double*)d_ws;
    int*    cnts  = (int*)((char*)d_ws + 16);
    float*  enorm = (float*)((char*)d_ws + 16 + NE * sizeof(int));
    float*  embT  = (float*)((char*)d_ws + 16 + NE * sizeof(int) + NE * sizeof(float));

    vq_prep<<<4, 256, 0, stream>>>(emb, enorm, embT, cnts, lacc);
    vq_main<<<512, 128, 0, stream>>>(z, emb, embT, enorm, cnts, lacc, out);
    vq_finalize<<<1, 1024, 0, stream>>>(cnts, lacc, out);
}